// Round 7
// baseline (327.345 us; speedup 1.0000x reference)
//
#include <hip/hip_runtime.h>
#include <hip/hip_bf16.h>
#include <stdint.h>

constexpr int A_ = 8, B_ = 32768, O_ = 256, C_ = 64, F_ = 320, E_ = 128;
constexpr int NRB = B_ / 128;  // 256 row-blocks of 128
constexpr int NBT = B_ / 16;   // 2048 batch tiles of 16

typedef __attribute__((ext_vector_type(8))) __bf16 bf16x8;
typedef __attribute__((ext_vector_type(4))) float f32x4;
union U4 { uint4 u; bf16x8 v; __bf16 b[8]; };

__device__ __forceinline__ float lrelu(float x){ return x >= 0.f ? x : 0.01f*x; }
__device__ __forceinline__ f32x4 mfma16(bf16x8 a, bf16x8 b, f32x4 c){
  return __builtin_amdgcn_mfma_f32_16x16x32_bf16(a, b, c, 0, 0, 0);
}
__device__ __forceinline__ bf16x8 pk8(f32x4 lo, f32x4 hi){
  U4 r;
  r.b[0]=(__bf16)lo[0]; r.b[1]=(__bf16)lo[1]; r.b[2]=(__bf16)lo[2]; r.b[3]=(__bf16)lo[3];
  r.b[4]=(__bf16)hi[0]; r.b[5]=(__bf16)hi[1]; r.b[6]=(__bf16)hi[2]; r.b[7]=(__bf16)hi[3];
  return r.v;
}
__device__ __forceinline__ bf16x8 pk8f(float4 a, float4 b){
  U4 r;
  r.b[0]=(__bf16)a.x; r.b[1]=(__bf16)a.y; r.b[2]=(__bf16)a.z; r.b[3]=(__bf16)a.w;
  r.b[4]=(__bf16)b.x; r.b[5]=(__bf16)b.y; r.b[6]=(__bf16)b.z; r.b[7]=(__bf16)b.w;
  return r.v;
}
__device__ __forceinline__ void gl_lds16(const void* g, void* s){
  __builtin_amdgcn_global_load_lds(
      (const __attribute__((address_space(1))) unsigned int*)g,
      (__attribute__((address_space(3))) unsigned int*)s, 16, 0, 0);
}
template<int N> __device__ __forceinline__ void vmwait(){
  asm volatile("s_waitcnt vmcnt(%0)" :: "n"(N) : "memory");
}
__device__ __forceinline__ void lgkm0(){ asm volatile("s_waitcnt lgkmcnt(0)" ::: "memory"); }
__device__ __forceinline__ void sbar(){ __builtin_amdgcn_s_barrier(); }
__device__ __forceinline__ void schb(){ __builtin_amdgcn_sched_barrier(0); }

// ------- fused: BN partial stats + bf16 swizzled x-pack + per-row argmax -------
// xpk tile per (a, rb, ks): [64 units (row pairs)][8 chunks of 16B], chunk for
// (row, lg') stored at ((row&1)*4 + lg') ^ ((row>>1)&7)  (pair-row XOR swizzle).
__global__ __launch_bounds__(256) void k_xstats(
    const float* __restrict__ obs, const float* __restrict__ act,
    __bf16* __restrict__ xpk, float* __restrict__ psum, float* __restrict__ psq,
    int* __restrict__ ids){
  __shared__ float tile[128*36];          // padded stride 36 -> conflict-free col reads
  __shared__ float sred[32][9], qred[32][9];
  const int a = blockIdx.y, rb = blockIdx.x, t = threadIdx.x;
  const int r = t >> 1, fh = t & 1;
  const size_t row0 = (size_t)a*B_ + (size_t)rb*128;
  float abest = -3.4e38f; int abi = 0;

  for (int c = 0; c < 10; ++c){
    const float* src = (c < 8) ? obs + (row0 + r)*O_ + c*32 + fh*16
                               : act + (row0 + r)*C_ + (c-8)*32 + fh*16;
    const float4 v0 = ((const float4*)src)[0];
    const float4 v1 = ((const float4*)src)[1];
    const float4 v2 = ((const float4*)src)[2];
    const float4 v3 = ((const float4*)src)[3];
    if (c >= 8){   // argmax over act (first-max semantics, ascending order)
      const int fb = (c-8)*32 + fh*16;
      const float4 vv[4] = {v0, v1, v2, v3};
      #pragma unroll
      for (int j = 0; j < 4; ++j){
        if (vv[j].x > abest){ abest = vv[j].x; abi = fb + j*4;   }
        if (vv[j].y > abest){ abest = vv[j].y; abi = fb + j*4+1; }
        if (vv[j].z > abest){ abest = vv[j].z; abi = fb + j*4+2; }
        if (vv[j].w > abest){ abest = vv[j].w; abi = fb + j*4+3; }
      }
    }
    // pack bf16, swizzled
    const int u = r >> 1, swz = u & 7;
    const int j0 = ((r&1)*4 + fh*2    ) ^ swz;
    const int j1 = ((r&1)*4 + fh*2 + 1) ^ swz;
    bf16x8* xb = (bf16x8*)xpk + ((size_t)(a*NRB + rb)*10 + c)*512 + u*8;
    xb[j0] = pk8f(v0, v1);
    xb[j1] = pk8f(v2, v3);
    // stats tile
    float* tr = tile + r*36 + fh*16;
    *(float4*)(tr)    = v0; *(float4*)(tr+4)  = v1;
    *(float4*)(tr+8)  = v2; *(float4*)(tr+12) = v3;
    __syncthreads();
    const int f = t & 31, g = t >> 5;
    float s = 0.f, q = 0.f;
    #pragma unroll 4
    for (int i = 0; i < 16; ++i){
      const float x = tile[(g*16+i)*36 + f];
      s += x; q += x*x;
    }
    sred[f][g] = s; qred[f][g] = q;
    __syncthreads();
    if (t < 32){
      float ss = 0.f, qq = 0.f;
      #pragma unroll
      for (int g2 = 0; g2 < 8; ++g2){ ss += sred[t][g2]; qq += qred[t][g2]; }
      psum[((size_t)a*NRB + rb)*F_ + c*32 + t] = ss;
      psq [((size_t)a*NRB + rb)*F_ + c*32 + t] = qq;
    }
    __syncthreads();
  }
  {
    const float ob = __shfl_xor(abest, 1, 64);
    const int   oi = __shfl_xor(abi,   1, 64);
    if (ob > abest || (ob == abest && oi < abi)){ abest = ob; abi = oi; }
    if (fh == 0) ids[row0 + r] = abi;
  }
}

__global__ void k_stats_final(const float* __restrict__ psum, const float* __restrict__ psq,
                              float* __restrict__ zscale, float* __restrict__ zshift){
  const int f = threadIdx.x, a = blockIdx.x;
  float s = 0.f, q = 0.f;
  for (int rb = 0; rb < NRB; ++rb){
    s += psum[((size_t)a*NRB + rb)*F_ + f];
    q += psq [((size_t)a*NRB + rb)*F_ + f];
  }
  const float mean = s * (1.0f / B_);
  float var = q * (1.0f / B_) - mean * mean;
  var = fmaxf(var, 0.0f);
  const float rs = rsqrtf(var + 1e-5f);
  zscale[a*F_ + f] = rs;
  zshift[a*F_ + f] = -mean * rs;
}

// ---- pack weights as MFMA A-fragments; BN folded into Ap + gsb ----
__global__ void k_prep_pack(const float* __restrict__ gW, const float* __restrict__ ggam,
                            const float* __restrict__ sW, const float* __restrict__ sgam,
                            const float* __restrict__ f1W, const float* __restrict__ f2W,
                            const float* __restrict__ Vm, const float* __restrict__ zscale,
                            __bf16* __restrict__ Ap, __bf16* __restrict__ Vp,
                            __bf16* __restrict__ B1p, __bf16* __restrict__ B2p){
  const int a = blockIdx.y;
  const int t0 = blockIdx.x*256 + threadIdx.x;
  constexpr int STR = 32*256;
  for (int i = t0; i < 10*16*64*8; i += STR){
    const int ks = i >> 13, mO = (i>>9)&15, l = (i>>3)&63, e = i&7;
    const int lg = l>>4, fo = mO*16 + (l&15), k = ks*32 + lg*8 + e;
    const float sc = zscale[a*F_ + k];
    float v;
    if (fo < 128) v = gW[(size_t)a*E_*F_ + (size_t)fo*F_ + k] * ggam[a*F_+k] * sc;
    else          v = (k < O_) ? sW[(size_t)a*E_*O_ + (size_t)(fo-128)*O_ + k] * sgam[a*O_+k] * sc : 0.f;
    Ap[(size_t)a*(10*16*64*8) + i] = (__bf16)v;
  }
  for (int i = t0; i < 8*8*64*8; i += STR){
    const int ks = i >> 12, mH = (i>>9)&7, l = (i>>3)&63, e = i&7;
    const int lg = l>>4, h = mH*16 + (l&15);
    const int f = 32*ks + 16*(e>>2) + 4*lg + (e&3);
    B1p[(size_t)a*(8*8*64*8) + i] = (__bf16)f1W[(size_t)a*E_*2*E_ + (size_t)h*2*E_ + f];
  }
  for (int i = t0; i < 4*4*64*8; i += STR){
    const int ks = i >> 11, mC = (i>>9)&3, l = (i>>3)&63, e = i&7;
    const int lg = l>>4, c = mC*16 + (l&15);
    const int f = 32*ks + 16*(e>>2) + 4*lg + (e&3);
    B2p[(size_t)a*(4*4*64*8) + i] = (__bf16)f2W[(size_t)a*C_*E_ + (size_t)c*E_ + f];
  }
  if (a == 0){
    for (int i = t0; i < 4*8*64*8; i += STR){
      const int ks = i >> 12, mV = (i>>9)&7, l = (i>>3)&63, e = i&7;
      const int lg = l>>4, vo = mV*16 + (l&15);
      const int f = 32*ks + 16*(e>>2) + 4*lg + (e&3);
      Vp[i] = (__bf16)Vm[(size_t)vo*E_ + f];
    }
  }
}

__global__ void k_prep_bias(const float* __restrict__ gW, const float* __restrict__ gb,
                            const float* __restrict__ ggam, const float* __restrict__ gbet,
                            const float* __restrict__ sW, const float* __restrict__ sb,
                            const float* __restrict__ sgam, const float* __restrict__ sbet,
                            const float* __restrict__ zshift, float* __restrict__ gsb){
  __shared__ float ww[F_];
  __shared__ float part[2][128];
  const int a = blockIdx.y, t = threadIdx.x;
  const int o = t & 127, h = t >> 7;
  if (blockIdx.x == 0){
    for (int f = t; f < F_; f += 256)
      ww[f] = gbet[a*F_+f] + ggam[a*F_+f]*zshift[a*F_+f];
    __syncthreads();
    float s = 0.f;
    #pragma unroll 4
    for (int f = h*160; f < h*160 + 160; f += 4){
      const float4 wv = *(const float4*)&gW[(size_t)a*E_*F_ + (size_t)o*F_ + f];
      s += wv.x*ww[f] + wv.y*ww[f+1] + wv.z*ww[f+2] + wv.w*ww[f+3];
    }
    part[h][o] = s;
    __syncthreads();
    if (t < 128) gsb[a*256 + t] = gb[a*E_+t] + part[0][t] + part[1][t];
  } else {
    for (int f = t; f < O_; f += 256)
      ww[f] = sbet[a*O_+f] + sgam[a*O_+f]*zshift[a*F_+f];
    __syncthreads();
    float s = 0.f;
    #pragma unroll 4
    for (int f = h*128; f < h*128 + 128; f += 4){
      const float4 wv = *(const float4*)&sW[(size_t)a*E_*O_ + (size_t)o*O_ + f];
      s += wv.x*ww[f] + wv.y*ww[f+1] + wv.z*ww[f+2] + wv.w*ww[f+3];
    }
    part[h][o] = s;
    __syncthreads();
    if (t < 128) gsb[a*256 + 128 + t] = sb[a*E_+t] + part[0][t] + part[1][t];
  }
}

// ------- Stage A v2: x via gl_lds (pre-swizzled bf16), w via reg loads, vmcnt(2) -------
__global__ __launch_bounds__(256) void k_stageA(
    const __bf16* __restrict__ xpk,
    const __bf16* __restrict__ Ap, const __bf16* __restrict__ Vp,
    const float* __restrict__ gsb,
    uint4* __restrict__ si_q, uint4* __restrict__ v_q){
  __shared__ __align__(16) char smem[32768];   // x: 3x8KB in [0,24K); e-frags use 32K later
  const int a = blockIdx.y, t = threadIdx.x;
  const int w = t>>6, l = t&63, l15 = l&15, lg = l>>4;
  const int rb = blockIdx.x;       // 128 rows
  const int bt0 = rb*8;
  const char* xT  = (const char*)xpk + ((size_t)(a*NRB + rb))*81920;
  const char* ApA = (const char*)Ap + (size_t)a*163840;
  // x frag base: unit (l15>>1), chunk ((l15&1)*4+lg) ^ ((l15>>1)&7)
  const int xcj = (((l15&1)<<2) | lg) ^ ((l15>>1)&7);
  const int xbase = (l15>>1)*128 + xcj*16;

  U4 wA[2][4];
  auto wload = [&](int ks){
    const uint4* p = (const uint4*)(ApA + ks*16384) + w*256 + l;
    U4* d = wA[ks&1];
    d[0].u = p[0]; d[1].u = p[64]; d[2].u = p[128]; d[3].u = p[192];
  };
  auto xstage = [&](int ks){
    const char* s = xT + ks*8192;
    char* d = smem + (ks%3)*8192;
    gl_lds16(s + ((w*2+0)*64+l)*16, d + (w*2+0)*1024);
    gl_lds16(s + ((w*2+1)*64+l)*16, d + (w*2+1)*1024);
  };

  f32x4 acc[4][8] = {};
  // prologue: w0, x0, x1 in flight; retire w0,x0
  wload(0); schb();
  xstage(0); xstage(1); schb();
  vmwait<2>(); sbar(); schb();

  #pragma unroll
  for (int ks = 0; ks < 10; ++ks){
    if (ks+1 < 10){ wload(ks+1); schb(); }
    if (ks+2 < 10){ xstage(ks+2); schb(); }
    const char* xb = smem + (ks%3)*8192;
    bf16x8 bfr[8];
    #pragma unroll
    for (int nt = 0; nt < 8; ++nt)
      bfr[nt] = *(const bf16x8*)(xb + nt*1024 + xbase);
    #pragma unroll
    for (int m = 0; m < 4; ++m){
      const bf16x8 af = wA[ks&1][m].v;
      #pragma unroll
      for (int nt = 0; nt < 8; ++nt)
        acc[m][nt] = mfma16(af, bfr[nt], acc[m][nt]);
    }
    schb();
    if (ks < 8)       vmwait<2>();
    else if (ks == 8) vmwait<0>();
    if (ks < 9){ sbar(); schb(); }
  }

  // bias + lrelu; feature = w*64 + m*16 + lg*4 + j
  const float* bE = gsb + a*256 + w*64 + lg*4;
  #pragma unroll
  for (int m = 0; m < 4; ++m){
    const float4 b = *(const float4*)(bE + m*16);
    #pragma unroll
    for (int nt = 0; nt < 8; ++nt){
      acc[m][nt][0] = lrelu(acc[m][nt][0] + b.x);
      acc[m][nt][1] = lrelu(acc[m][nt][1] + b.y);
      acc[m][nt][2] = lrelu(acc[m][nt][2] + b.z);
      acc[m][nt][3] = lrelu(acc[m][nt][3] + b.w);
    }
  }
  sbar();   // all k-loop LDS reads done; smem reusable for e-frags

  if (w < 2){
    // e-frags -> LDS, pi layout (feature 32*kv + 16(e>>2)+4lg+(e&3))
    #pragma unroll
    for (int jp = 0; jp < 2; ++jp){
      const int kv = 2*w + jp;
      #pragma unroll
      for (int nt = 0; nt < 8; ++nt)
        *(bf16x8*)(smem + ((kv*8 + nt)*64 + l)*16) = pk8(acc[2*jp][nt], acc[2*jp+1][nt]);
    }
  } else {
    #pragma unroll
    for (int jp = 0; jp < 2; ++jp){
      const int j = 2*(w-2) + jp;
      #pragma unroll
      for (int nt = 0; nt < 8; ++nt){
        U4 u; u.v = pk8(acc[2*jp][nt], acc[2*jp+1][nt]);
        si_q[(((size_t)a*NBT + bt0 + nt)*4 + j)*64 + l] = u.u;
      }
    }
  }
  lgkm0(); sbar(); schb();

  // v-GEMM: wave w owns v-outputs [w*32, w*32+32)
  const uint4* Vq = (const uint4*)Vp;
  f32x4 accv[2][8] = {};
  #pragma unroll
  for (int kv = 0; kv < 4; ++kv){
    U4 a0, a1;
    a0.u = Vq[(kv*8 + w*2 + 0)*64 + l];
    a1.u = Vq[(kv*8 + w*2 + 1)*64 + l];
    bf16x8 bv[8];
    #pragma unroll
    for (int nt = 0; nt < 8; ++nt)
      bv[nt] = *(const bf16x8*)(smem + ((kv*8 + nt)*64 + l)*16);
    #pragma unroll
    for (int nt = 0; nt < 8; ++nt){
      accv[0][nt] = mfma16(a0.v, bv[nt], accv[0][nt]);
      accv[1][nt] = mfma16(a1.v, bv[nt], accv[1][nt]);
    }
  }
  #pragma unroll
  for (int nt = 0; nt < 8; ++nt){
    f32x4 lo, hi;
    #pragma unroll
    for (int e = 0; e < 4; ++e){ lo[e] = lrelu(accv[0][nt][e]); hi[e] = lrelu(accv[1][nt][e]); }
    U4 u; u.v = pk8(lo, hi);
    v_q[(((size_t)a*NBT + bt0 + nt)*4 + w)*64 + l] = u.u;
  }
}

// ---------------- vsum over agents (bf16 frags) ----------------
__global__ void k_vsum(const uint4* __restrict__ v_q, uint4* __restrict__ vsum_q){
  const size_t i = (size_t)blockIdx.x*256 + threadIdx.x;
  const size_t per_a = (size_t)NBT*4*64;
  float s[8] = {0,0,0,0,0,0,0,0};
  #pragma unroll
  for (int aa = 0; aa < 8; ++aa){
    U4 u; u.u = v_q[aa*per_a + i];
    #pragma unroll
    for (int e = 0; e < 8; ++e) s[e] += (float)u.b[e];
  }
  U4 o;
  #pragma unroll
  for (int e = 0; e < 8; ++e) o.b[e] = (__bf16)s[e];
  vsum_q[i] = o.u;
}

// ---------------- Stage C: x = vsum - v | si -> h -> q -> gather ----------------
__global__ __launch_bounds__(256, 2) void k_stageC(
    const uint4* __restrict__ v_q, const uint4* __restrict__ si_q,
    const uint4* __restrict__ vsum_q,
    const __bf16* __restrict__ B1p, const __bf16* __restrict__ B2p,
    const float* __restrict__ f1b, const float* __restrict__ f2b,
    const int* __restrict__ ids, float* __restrict__ out){
  __shared__ __align__(16) char wsm[2*8192];
  __shared__ float qs[4][64][17];
  const int a = blockIdx.y, t = threadIdx.x;
  const int w = t>>6, l = t&63, l15 = l&15, lg = l>>4;
  const int btw = blockIdx.x*16 + w*4;
  const char* B1A = (const char*)B1p + (size_t)a*65536;
  const size_t vbase = (size_t)a*NBT*4*64;

  uint4 qA[4], qB[4], sA[4], sB[4];

  auto wstage = [&](int ks, char* dst){
    const char* src = B1A + ks*8192;
    #pragma unroll
    for (int i = 0; i < 2; ++i)
      gl_lds16(src + (w*2+i)*1024 + l*16, dst + (w*2+i)*1024);
  };
  auto bload = [&](int ks, uint4* qv, uint4* sv){
    if (ks < 4){
      #pragma unroll
      for (int nt = 0; nt < 4; ++nt){
        const size_t idx = ((size_t)(btw+nt)*4 + ks)*64 + l;
        qv[nt] = v_q[vbase + idx];
        sv[nt] = vsum_q[idx];
      }
    } else {
      #pragma unroll
      for (int nt = 0; nt < 4; ++nt)
        qv[nt] = si_q[vbase + ((size_t)(btw+nt)*4 + (ks-4))*64 + l];
    }
  };
  auto bmake = [&](int ks, const uint4* qv, const uint4* sv, bf16x8* bf){
    if (ks < 4){
      #pragma unroll
      for (int nt = 0; nt < 4; ++nt){
        U4 s, v; s.u = sv[nt]; v.u = qv[nt];
        f32x4 lo, hi;
        #pragma unroll
        for (int e = 0; e < 4; ++e){
          lo[e] = (float)s.b[e]   - (float)v.b[e];
          hi[e] = (float)s.b[e+4] - (float)v.b[e+4];
        }
        bf[nt] = pk8(lo, hi);
      }
    } else {
      #pragma unroll
      for (int nt = 0; nt < 4; ++nt){ U4 u; u.u = qv[nt]; bf[nt] = u.v; }
    }
  };

  f32x4 hacc[8][4] = {};
  wstage(0, wsm); schb();
  bload(0, qA, sA); schb();
  bload(1, qB, sB);
  vmwait<8>();
  sbar(); schb();

  #pragma unroll
  for (int ks = 0; ks < 8; ++ks){
    bf16x8 bf[4];
    bmake(ks, (ks&1) ? qB : qA, (ks&1) ? sB : sA, bf);
    if (ks+1 < 8){ wstage(ks+1, wsm + ((ks+1)&1)*8192); schb(); }
    if (ks+2 < 8) bload(ks+2, (ks&1) ? qB : qA, (ks&1) ? sB : sA);
    {
      const bf16x8* wc = (const bf16x8*)(wsm + (ks&1)*8192);
      #pragma unroll
      for (int m = 0; m < 8; ++m){
        const bf16x8 af = wc[m*64 + l];
        #pragma unroll
        for (int nt = 0; nt < 4; ++nt)
          hacc[m][nt] = mfma16(af, bf[nt], hacc[m][nt]);
      }
    }
    schb();
    if (ks <= 1)      vmwait<8>();
    else if (ks <= 5) vmwait<4>();
    else if (ks == 6) vmwait<0>();
    if (ks < 7){ sbar(); schb(); }
  }

  bf16x8 hb[4][4];
  const float* bH = f1b + a*E_ + lg*4;
  #pragma unroll
  for (int kq = 0; kq < 4; ++kq){
    const float4 b0v = *(const float4*)(bH + (2*kq)*16);
    const float4 b1v = *(const float4*)(bH + (2*kq+1)*16);
    #pragma unroll
    for (int nt = 0; nt < 4; ++nt){
      f32x4 lo, hi;
      lo[0]=lrelu(hacc[2*kq][nt][0]+b0v.x); lo[1]=lrelu(hacc[2*kq][nt][1]+b0v.y);
      lo[2]=lrelu(hacc[2*kq][nt][2]+b0v.z); lo[3]=lrelu(hacc[2*kq][nt][3]+b0v.w);
      hi[0]=lrelu(hacc[2*kq+1][nt][0]+b1v.x); hi[1]=lrelu(hacc[2*kq+1][nt][1]+b1v.y);
      hi[2]=lrelu(hacc[2*kq+1][nt][2]+b1v.z); hi[3]=lrelu(hacc[2*kq+1][nt][3]+b1v.w);
      hb[kq][nt] = pk8(lo, hi);
    }
  }
  const uint4* A2q = (const uint4*)(B2p + (size_t)a*(4*4*64*8));
  f32x4 accq[4][4] = {};
  #pragma unroll
  for (int kq = 0; kq < 4; ++kq){
    #pragma unroll
    for (int mC = 0; mC < 4; ++mC){
      U4 af; af.u = A2q[(kq*4 + mC)*64 + l];
      #pragma unroll
      for (int nt = 0; nt < 4; ++nt)
        accq[mC][nt] = mfma16(af.v, hb[kq][nt], accq[mC][nt]);
    }
  }
  const float* bQ = f2b + a*C_ + lg*4;
  float4 qb[4];
  #pragma unroll
  for (int mC = 0; mC < 4; ++mC) qb[mC] = *(const float4*)(bQ + mC*16);
  #pragma unroll
  for (int nt = 0; nt < 4; ++nt){
    #pragma unroll
    for (int mC = 0; mC < 4; ++mC){
      qs[w][mC*16 + lg*4 + 0][l15] = accq[mC][nt][0] + qb[mC].x;
      qs[w][mC*16 + lg*4 + 1][l15] = accq[mC][nt][1] + qb[mC].y;
      qs[w][mC*16 + lg*4 + 2][l15] = accq[mC][nt][2] + qb[mC].z;
      qs[w][mC*16 + lg*4 + 3][l15] = accq[mC][nt][3] + qb[mC].w;
    }
    lgkm0();
    if (l < 16){
      const size_t row = (size_t)(btw + nt)*16 + l;
      const int id = ids[(size_t)a*B_ + row];
      out[(size_t)a*B_ + row] = qs[w][id][l];
    }
    lgkm0();
  }
}

extern "C" void kernel_launch(void* const* d_in, const int* in_sizes, int n_in,
                              void* d_out, int out_size, void* d_ws, size_t ws_size,
                              hipStream_t stream) {
  const float* obs  = (const float*)d_in[0];
  const float* act  = (const float*)d_in[1];
  const float* ggam = (const float*)d_in[2];
  const float* gbet = (const float*)d_in[3];
  const float* gW   = (const float*)d_in[4];
  const float* gb   = (const float*)d_in[5];
  const float* sgam = (const float*)d_in[6];
  const float* sbet = (const float*)d_in[7];
  const float* sW   = (const float*)d_in[8];
  const float* sb   = (const float*)d_in[9];
  const float* f1W  = (const float*)d_in[10];
  const float* f1b  = (const float*)d_in[11];
  const float* f2W  = (const float*)d_in[12];
  const float* f2b  = (const float*)d_in[13];
  // d_in[14]=Wq, d_in[15]=Wk dead (softmax over length-1 axis == 1)
  const float* Vm   = (const float*)d_in[16];
  float* out = (float*)d_out;

  char* base = (char*)d_ws; size_t off = 0;
  auto alloc = [&](size_t bytes) -> void* {
    off = (off + 255) & ~(size_t)255; void* p = base + off; off += bytes; return p;
  };
  float* psum    = (float*)alloc((size_t)A_*NRB*F_*4);
  float* psq     = (float*)alloc((size_t)A_*NRB*F_*4);
  float* zscale  = (float*)alloc((size_t)A_*F_*4);
  float* zshift  = (float*)alloc((size_t)A_*F_*4);
  float* gsb     = (float*)alloc((size_t)A_*256*4);
  __bf16* xpk    = (__bf16*)alloc((size_t)A_*NRB*10*512*16);
  __bf16* Ap     = (__bf16*)alloc((size_t)A_*10*16*64*8*2);
  __bf16* Vp     = (__bf16*)alloc((size_t)4*8*64*8*2);
  __bf16* B1p    = (__bf16*)alloc((size_t)A_*8*8*64*8*2);
  __bf16* B2p    = (__bf16*)alloc((size_t)A_*4*4*64*8*2);
  uint4* si_q    = (uint4*)alloc((size_t)A_*NBT*4*64*16);
  uint4* v_q     = (uint4*)alloc((size_t)A_*NBT*4*64*16);
  uint4* vsum_q  = (uint4*)alloc((size_t)NBT*4*64*16);
  int*   ids     = (int*)alloc((size_t)A_*B_*4);
  (void)ws_size; (void)in_sizes; (void)n_in; (void)out_size;

  k_xstats<<<dim3(NRB, A_), 256, 0, stream>>>(obs, act, xpk, psum, psq, ids);
  k_stats_final<<<A_, F_, 0, stream>>>(psum, psq, zscale, zshift);
  k_prep_pack<<<dim3(32, A_), 256, 0, stream>>>(gW, ggam, sW, sgam, f1W, f2W, Vm,
                                                zscale, Ap, Vp, B1p, B2p);
  k_prep_bias<<<dim3(2, A_), 256, 0, stream>>>(gW, gb, ggam, gbet, sW, sb, sgam, sbet,
                                               zshift, gsb);
  k_stageA<<<dim3(NRB, A_), 256, 0, stream>>>(xpk, Ap, Vp, gsb, si_q, v_q);
  k_vsum<<<(NBT*4*64)/256, 256, 0, stream>>>(v_q, vsum_q);
  k_stageC<<<dim3(NBT/16, A_), 256, 0, stream>>>(v_q, si_q, vsum_q, B1p, B2p,
                                                 f1b, f2b, ids, out);
}

// Round 8
// 256.172 us; speedup vs baseline: 1.2778x; 1.2778x over previous
//
#include <hip/hip_runtime.h>
#include <hip/hip_bf16.h>
#include <stdint.h>

constexpr int A_ = 8, B_ = 32768, O_ = 256, C_ = 64, F_ = 320, E_ = 128;
constexpr int NCH = 128, CHROWS = B_ / NCH;
constexpr int NBT = B_ / 16;   // 2048 batch tiles of 16

typedef __attribute__((ext_vector_type(8))) __bf16 bf16x8;
typedef __attribute__((ext_vector_type(4))) float f32x4;
union U4 { uint4 u; bf16x8 v; __bf16 b[8]; };

__device__ __forceinline__ float lrelu(float x){ return x >= 0.f ? x : 0.01f*x; }
__device__ __forceinline__ f32x4 mfma16(bf16x8 a, bf16x8 b, f32x4 c){
  return __builtin_amdgcn_mfma_f32_16x16x32_bf16(a, b, c, 0, 0, 0);
}
__device__ __forceinline__ bf16x8 pk8(f32x4 lo, f32x4 hi){
  U4 r;
  r.b[0]=(__bf16)lo[0]; r.b[1]=(__bf16)lo[1]; r.b[2]=(__bf16)lo[2]; r.b[3]=(__bf16)lo[3];
  r.b[4]=(__bf16)hi[0]; r.b[5]=(__bf16)hi[1]; r.b[6]=(__bf16)hi[2]; r.b[7]=(__bf16)hi[3];
  return r.v;
}
__device__ __forceinline__ bf16x8 pk8f(float4 a, float4 b){
  U4 r;
  r.b[0]=(__bf16)a.x; r.b[1]=(__bf16)a.y; r.b[2]=(__bf16)a.z; r.b[3]=(__bf16)a.w;
  r.b[4]=(__bf16)b.x; r.b[5]=(__bf16)b.y; r.b[6]=(__bf16)b.z; r.b[7]=(__bf16)b.w;
  return r.v;
}
__device__ __forceinline__ void gl_lds16(const void* g, void* s){
  __builtin_amdgcn_global_load_lds(
      (const __attribute__((address_space(1))) unsigned int*)g,
      (__attribute__((address_space(3))) unsigned int*)s, 16, 0, 0);
}
template<int N> __device__ __forceinline__ void vmwait(){
  asm volatile("s_waitcnt vmcnt(%0)" :: "n"(N) : "memory");
}
__device__ __forceinline__ void lgkm0(){ asm volatile("s_waitcnt lgkmcnt(0)" ::: "memory"); }
__device__ __forceinline__ void sbar(){ __builtin_amdgcn_s_barrier(); }
__device__ __forceinline__ void schb(){ __builtin_amdgcn_sched_barrier(0); }

// ---------------- Stage 0: BN stats + fused per-row argmax(act) ----------------
__global__ void k_stats_partial(const float* __restrict__ obs,
                                const float* __restrict__ act,
                                float* __restrict__ psum, float* __restrict__ psq,
                                int* __restrict__ ids){
  const int f = threadIdx.x, ch = blockIdx.x, a = blockIdx.y;
  const size_t b0 = (size_t)ch * CHROWS;
  float s = 0.f, q = 0.f;
  if (f < O_){
    const float* p = obs + ((size_t)a*B_ + b0)*O_ + f;
    for (int i = 0; i < CHROWS; ++i){ float x = p[(size_t)i*O_]; s += x; q += x*x; }
  } else {
    const float* p = act + ((size_t)a*B_ + b0)*C_ + (f - O_);
    for (int i = 0; i < CHROWS; ++i){ float x = p[(size_t)i*C_]; s += x; q += x*x; }
  }
  psum[((size_t)a*NCH + ch)*F_ + f] = s;
  psq [((size_t)a*NCH + ch)*F_ + f] = q;
  if (f < CHROWS){
    const float4* ar = (const float4*)(act + ((size_t)a*B_ + b0 + f)*C_);
    float best = -3.4e38f; int bi = 0;
    #pragma unroll 4
    for (int j = 0; j < 16; ++j){
      const float4 v = ar[j];
      const int c0 = j*4;
      if (v.x > best){ best = v.x; bi = c0;   }
      if (v.y > best){ best = v.y; bi = c0+1; }
      if (v.z > best){ best = v.z; bi = c0+2; }
      if (v.w > best){ best = v.w; bi = c0+3; }
    }
    ids[(size_t)a*B_ + b0 + f] = bi;
  }
}

__global__ void k_stats_final(const float* __restrict__ psum, const float* __restrict__ psq,
                              float* __restrict__ zscale, float* __restrict__ zshift){
  const int f = threadIdx.x, a = blockIdx.x;
  float s = 0.f, q = 0.f;
  for (int ch = 0; ch < NCH; ++ch){
    s += psum[((size_t)a*NCH + ch)*F_ + f];
    q += psq [((size_t)a*NCH + ch)*F_ + f];
  }
  const float mean = s * (1.0f / B_);
  float var = q * (1.0f / B_) - mean * mean;
  var = fmaxf(var, 0.0f);
  const float rs = rsqrtf(var + 1e-5f);
  zscale[a*F_ + f] = rs;
  zshift[a*F_ + f] = -mean * rs;
}

// ---- pack weights as MFMA A-fragments; BN folded into Ap + gsb ----
__global__ void k_prep_pack(const float* __restrict__ gW, const float* __restrict__ ggam,
                            const float* __restrict__ sW, const float* __restrict__ sgam,
                            const float* __restrict__ f1W, const float* __restrict__ f2W,
                            const float* __restrict__ Vm, const float* __restrict__ zscale,
                            __bf16* __restrict__ Ap, __bf16* __restrict__ Vp,
                            __bf16* __restrict__ B1p, __bf16* __restrict__ B2p){
  const int a = blockIdx.y;
  const int t0 = blockIdx.x*256 + threadIdx.x;
  constexpr int STR = 32*256;
  for (int i = t0; i < 10*16*64*8; i += STR){
    const int ks = i >> 13, mO = (i>>9)&15, l = (i>>3)&63, e = i&7;
    const int lg = l>>4, fo = mO*16 + (l&15), k = ks*32 + lg*8 + e;
    const float sc = zscale[a*F_ + k];
    float v;
    if (fo < 128) v = gW[(size_t)a*E_*F_ + (size_t)fo*F_ + k] * ggam[a*F_+k] * sc;
    else          v = (k < O_) ? sW[(size_t)a*E_*O_ + (size_t)(fo-128)*O_ + k] * sgam[a*O_+k] * sc : 0.f;
    Ap[(size_t)a*(10*16*64*8) + i] = (__bf16)v;
  }
  for (int i = t0; i < 8*8*64*8; i += STR){
    const int ks = i >> 12, mH = (i>>9)&7, l = (i>>3)&63, e = i&7;
    const int lg = l>>4, h = mH*16 + (l&15);
    const int f = 32*ks + 16*(e>>2) + 4*lg + (e&3);
    B1p[(size_t)a*(8*8*64*8) + i] = (__bf16)f1W[(size_t)a*E_*2*E_ + (size_t)h*2*E_ + f];
  }
  for (int i = t0; i < 4*4*64*8; i += STR){
    const int ks = i >> 11, mC = (i>>9)&3, l = (i>>3)&63, e = i&7;
    const int lg = l>>4, c = mC*16 + (l&15);
    const int f = 32*ks + 16*(e>>2) + 4*lg + (e&3);
    B2p[(size_t)a*(4*4*64*8) + i] = (__bf16)f2W[(size_t)a*C_*E_ + (size_t)c*E_ + f];
  }
  if (a == 0){
    for (int i = t0; i < 4*8*64*8; i += STR){
      const int ks = i >> 12, mV = (i>>9)&7, l = (i>>3)&63, e = i&7;
      const int lg = l>>4, vo = mV*16 + (l&15);
      const int f = 32*ks + 16*(e>>2) + 4*lg + (e&3);
      Vp[i] = (__bf16)Vm[(size_t)vo*E_ + f];
    }
  }
}

__global__ void k_prep_bias(const float* __restrict__ gW, const float* __restrict__ gb,
                            const float* __restrict__ ggam, const float* __restrict__ gbet,
                            const float* __restrict__ sW, const float* __restrict__ sb,
                            const float* __restrict__ sgam, const float* __restrict__ sbet,
                            const float* __restrict__ zshift, float* __restrict__ gsb){
  __shared__ float ww[F_];
  __shared__ float part[2][128];
  const int a = blockIdx.y, t = threadIdx.x;
  const int o = t & 127, h = t >> 7;
  if (blockIdx.x == 0){
    for (int f = t; f < F_; f += 256)
      ww[f] = gbet[a*F_+f] + ggam[a*F_+f]*zshift[a*F_+f];
    __syncthreads();
    float s = 0.f;
    #pragma unroll 4
    for (int f = h*160; f < h*160 + 160; f += 4){
      const float4 wv = *(const float4*)&gW[(size_t)a*E_*F_ + (size_t)o*F_ + f];
      s += wv.x*ww[f] + wv.y*ww[f+1] + wv.z*ww[f+2] + wv.w*ww[f+3];
    }
    part[h][o] = s;
    __syncthreads();
    if (t < 128) gsb[a*256 + t] = gb[a*E_+t] + part[0][t] + part[1][t];
  } else {
    for (int f = t; f < O_; f += 256)
      ww[f] = sbet[a*O_+f] + sgam[a*O_+f]*zshift[a*F_+f];
    __syncthreads();
    float s = 0.f;
    #pragma unroll 4
    for (int f = h*128; f < h*128 + 128; f += 4){
      const float4 wv = *(const float4*)&sW[(size_t)a*E_*O_ + (size_t)o*O_ + f];
      s += wv.x*ww[f] + wv.y*ww[f+1] + wv.z*ww[f+2] + wv.w*ww[f+3];
    }
    part[h][o] = s;
    __syncthreads();
    if (t < 128) gsb[a*256 + 128 + t] = sb[a*E_+t] + part[0][t] + part[1][t];
  }
}

// ------- Stage A (round-6 structure) + REVERSED block order for L3 tail hits -------
__global__ __launch_bounds__(256, 2) void k_stageA(
    const float* __restrict__ obs, const float* __restrict__ act,
    const __bf16* __restrict__ Ap, const __bf16* __restrict__ Vp,
    const float* __restrict__ gsb,
    uint4* __restrict__ si_q, uint4* __restrict__ v_q){
  constexpr int BUF = 26624;        // 16 KB weights + 10240 B x (128 rows * 80 B)
  __shared__ __align__(16) char smem[2*BUF];
  const int a = (A_-1) - blockIdx.y;                 // reversed: read L3-resident tail first
  const int t = threadIdx.x;
  const int w = t>>6, l = t&63, l15 = l&15, lg = l>>4;
  const int bt0 = ((NBT/8 - 1) - blockIdx.x)*8;      // reversed row-blocks
  const size_t grow0 = (size_t)a*B_ + (size_t)bt0*16;
  const char* ApA = (const char*)Ap + (size_t)a*163840;
  const int xr = t>>1, kc0 = (t&1)*2;
  const float* obsrow = obs + (grow0 + xr)*O_;
  const float* actrow = act + (grow0 + xr)*C_;

  float4 xA[4], xB[4];

  auto wstage = [&](int ks, char* buf){
    const char* src = ApA + ks*16384;
    #pragma unroll
    for (int i = 0; i < 4; ++i)
      gl_lds16(src + (w*4+i)*1024 + l*16, buf + (w*4+i)*1024);
  };
  auto xload = [&](int ks, float4* d){
    const float* s = (ks < 8) ? (obsrow + ks*32 + kc0*8) : (actrow + (ks-8)*32 + kc0*8);
    d[0] = ((const float4*)s)[0]; d[1] = ((const float4*)s)[1];
    d[2] = ((const float4*)s)[2]; d[3] = ((const float4*)s)[3];
  };
  auto xwrite = [&](char* buf, const float4* d){
    *(bf16x8*)(buf + 16384 + xr*80 + kc0*16)     = pk8f(d[0], d[1]);
    *(bf16x8*)(buf + 16384 + xr*80 + (kc0+1)*16) = pk8f(d[2], d[3]);
  };

  f32x4 acc[4][8] = {};

  // prologue
  wstage(0, smem); schb();
  xload(0, xA);
  vmwait<0>();
  xwrite(smem, xA);
  xload(1, xB);
  lgkm0(); sbar(); schb();

  #pragma unroll
  for (int ks = 0; ks < 10; ++ks){
    char* cur = smem + (ks&1)*BUF;
    char* nxt = smem + ((ks+1)&1)*BUF;
    if (ks+1 < 10){ wstage(ks+1, nxt); schb(); }
    if (ks+2 < 10) xload(ks+2, (ks&1) ? xB : xA);
    {
      const bf16x8* wc = (const bf16x8*)cur;
      const char* xb = cur + 16384;
      bf16x8 bfr[8];
      #pragma unroll
      for (int nt = 0; nt < 8; ++nt)
        bfr[nt] = *(const bf16x8*)(xb + (nt*16 + l15)*80 + lg*16);
      #pragma unroll
      for (int m = 0; m < 4; ++m){
        const bf16x8 af = wc[(w*4+m)*64 + l];
        #pragma unroll
        for (int nt = 0; nt < 8; ++nt)
          acc[m][nt] = mfma16(af, bfr[nt], acc[m][nt]);
      }
    }
    schb();
    if (ks <= 7)      vmwait<4>();
    else if (ks == 8) vmwait<0>();
    if (ks+1 < 10) xwrite(nxt, (ks&1) ? xA : xB);
    if (ks < 9){ lgkm0(); sbar(); schb(); }
  }

  // bias + lrelu; feature = w*64 + m*16 + lg*4 + j
  const float* bE = gsb + a*256 + w*64 + lg*4;
  #pragma unroll
  for (int m = 0; m < 4; ++m){
    const float4 b = *(const float4*)(bE + m*16);
    #pragma unroll
    for (int nt = 0; nt < 8; ++nt){
      acc[m][nt][0] = lrelu(acc[m][nt][0] + b.x);
      acc[m][nt][1] = lrelu(acc[m][nt][1] + b.y);
      acc[m][nt][2] = lrelu(acc[m][nt][2] + b.z);
      acc[m][nt][3] = lrelu(acc[m][nt][3] + b.w);
    }
  }
  sbar();   // all k-loop LDS reads done; smem reusable for e-frags

  if (w < 2){
    #pragma unroll
    for (int jp = 0; jp < 2; ++jp){
      const int kv = 2*w + jp;
      #pragma unroll
      for (int nt = 0; nt < 8; ++nt)
        *(bf16x8*)(smem + ((kv*8 + nt)*64 + l)*16) = pk8(acc[2*jp][nt], acc[2*jp+1][nt]);
    }
  } else {
    #pragma unroll
    for (int jp = 0; jp < 2; ++jp){
      const int j = 2*(w-2) + jp;
      #pragma unroll
      for (int nt = 0; nt < 8; ++nt){
        U4 u; u.v = pk8(acc[2*jp][nt], acc[2*jp+1][nt]);
        si_q[(((size_t)a*NBT + bt0 + nt)*4 + j)*64 + l] = u.u;
      }
    }
  }
  lgkm0(); sbar(); schb();

  // v-GEMM: wave w owns v-outputs [w*32, w*32+32)
  const uint4* Vq = (const uint4*)Vp;
  f32x4 accv[2][8] = {};
  #pragma unroll
  for (int kv = 0; kv < 4; ++kv){
    U4 a0, a1;
    a0.u = Vq[(kv*8 + w*2 + 0)*64 + l];
    a1.u = Vq[(kv*8 + w*2 + 1)*64 + l];
    bf16x8 bv[8];
    #pragma unroll
    for (int nt = 0; nt < 8; ++nt)
      bv[nt] = *(const bf16x8*)(smem + ((kv*8 + nt)*64 + l)*16);
    #pragma unroll
    for (int nt = 0; nt < 8; ++nt){
      accv[0][nt] = mfma16(a0.v, bv[nt], accv[0][nt]);
      accv[1][nt] = mfma16(a1.v, bv[nt], accv[1][nt]);
    }
  }
  #pragma unroll
  for (int nt = 0; nt < 8; ++nt){
    f32x4 lo, hi;
    #pragma unroll
    for (int e = 0; e < 4; ++e){ lo[e] = lrelu(accv[0][nt][e]); hi[e] = lrelu(accv[1][nt][e]); }
    U4 u; u.v = pk8(lo, hi);
    v_q[(((size_t)a*NBT + bt0 + nt)*4 + w)*64 + l] = u.u;
  }
}

// ---------------- vsum over agents (bf16 frags) ----------------
__global__ void k_vsum(const uint4* __restrict__ v_q, uint4* __restrict__ vsum_q){
  const size_t i = (size_t)blockIdx.x*256 + threadIdx.x;
  const size_t per_a = (size_t)NBT*4*64;
  float s[8] = {0,0,0,0,0,0,0,0};
  #pragma unroll
  for (int aa = 0; aa < 8; ++aa){
    U4 u; u.u = v_q[aa*per_a + i];
    #pragma unroll
    for (int e = 0; e < 8; ++e) s[e] += (float)u.b[e];
  }
  U4 o;
  #pragma unroll
  for (int e = 0; e < 8; ++e) o.b[e] = (__bf16)s[e];
  vsum_q[i] = o.u;
}

// ------- Stage C: nt=2 per wave (halved VGPR -> better occupancy), grid x2 -------
__global__ __launch_bounds__(256, 2) void k_stageC(
    const uint4* __restrict__ v_q, const uint4* __restrict__ si_q,
    const uint4* __restrict__ vsum_q,
    const __bf16* __restrict__ B1p, const __bf16* __restrict__ B2p,
    const float* __restrict__ f1b, const float* __restrict__ f2b,
    const int* __restrict__ ids, float* __restrict__ out){
  __shared__ __align__(16) char wsm[2*8192];
  __shared__ float qs[4][64][17];
  const int a = blockIdx.y, t = threadIdx.x;
  const int w = t>>6, l = t&63, l15 = l&15, lg = l>>4;
  const int btw = blockIdx.x*8 + w*2;   // wave's 2 batch tiles (32 rows)
  const char* B1A = (const char*)B1p + (size_t)a*65536;
  const size_t vbase = (size_t)a*NBT*4*64;

  uint4 qA[2], qB[2], sA[2], sB[2];

  auto wstage = [&](int ks, char* dst){
    const char* src = B1A + ks*8192;
    #pragma unroll
    for (int i = 0; i < 2; ++i)
      gl_lds16(src + (w*2+i)*1024 + l*16, dst + (w*2+i)*1024);
  };
  auto bload = [&](int ks, uint4* qv, uint4* sv){
    if (ks < 4){
      #pragma unroll
      for (int nt = 0; nt < 2; ++nt){
        const size_t idx = ((size_t)(btw+nt)*4 + ks)*64 + l;
        qv[nt] = v_q[vbase + idx];
        sv[nt] = vsum_q[idx];
      }
    } else {
      #pragma unroll
      for (int nt = 0; nt < 2; ++nt)
        qv[nt] = si_q[vbase + ((size_t)(btw+nt)*4 + (ks-4))*64 + l];
    }
  };
  auto bmake = [&](int ks, const uint4* qv, const uint4* sv, bf16x8* bf){
    if (ks < 4){
      #pragma unroll
      for (int nt = 0; nt < 2; ++nt){
        U4 s, v; s.u = sv[nt]; v.u = qv[nt];
        f32x4 lo, hi;
        #pragma unroll
        for (int e = 0; e < 4; ++e){
          lo[e] = (float)s.b[e]   - (float)v.b[e];
          hi[e] = (float)s.b[e+4] - (float)v.b[e+4];
        }
        bf[nt] = pk8(lo, hi);
      }
    } else {
      #pragma unroll
      for (int nt = 0; nt < 2; ++nt){ U4 u; u.u = qv[nt]; bf[nt] = u.v; }
    }
  };

  f32x4 hacc[8][2] = {};
  wstage(0, wsm); schb();
  bload(0, qA, sA); schb();
  bload(1, qB, sB);
  vmwait<4>();
  sbar(); schb();

  #pragma unroll
  for (int ks = 0; ks < 8; ++ks){
    bf16x8 bf[2];
    bmake(ks, (ks&1) ? qB : qA, (ks&1) ? sB : sA, bf);
    if (ks+1 < 8){ wstage(ks+1, wsm + ((ks+1)&1)*8192); schb(); }
    if (ks+2 < 8) bload(ks+2, (ks&1) ? qB : qA, (ks&1) ? sB : sA);
    {
      const bf16x8* wc = (const bf16x8*)(wsm + (ks&1)*8192);
      #pragma unroll
      for (int m = 0; m < 8; ++m){
        const bf16x8 af = wc[m*64 + l];
        hacc[m][0] = mfma16(af, bf[0], hacc[m][0]);
        hacc[m][1] = mfma16(af, bf[1], hacc[m][1]);
      }
    }
    schb();
    if (ks <= 1)      vmwait<4>();   // leave bload(ks+2) [4 loads] in flight
    else if (ks <= 5) vmwait<2>();   // leave bload(ks+2) [2 loads] in flight
    else if (ks == 6) vmwait<0>();
    if (ks < 7){ sbar(); schb(); }
  }

  bf16x8 hb[4][2];
  const float* bH = f1b + a*E_ + lg*4;
  #pragma unroll
  for (int kq = 0; kq < 4; ++kq){
    const float4 b0v = *(const float4*)(bH + (2*kq)*16);
    const float4 b1v = *(const float4*)(bH + (2*kq+1)*16);
    #pragma unroll
    for (int nt = 0; nt < 2; ++nt){
      f32x4 lo, hi;
      lo[0]=lrelu(hacc[2*kq][nt][0]+b0v.x); lo[1]=lrelu(hacc[2*kq][nt][1]+b0v.y);
      lo[2]=lrelu(hacc[2*kq][nt][2]+b0v.z); lo[3]=lrelu(hacc[2*kq][nt][3]+b0v.w);
      hi[0]=lrelu(hacc[2*kq+1][nt][0]+b1v.x); hi[1]=lrelu(hacc[2*kq+1][nt][1]+b1v.y);
      hi[2]=lrelu(hacc[2*kq+1][nt][2]+b1v.z); hi[3]=lrelu(hacc[2*kq+1][nt][3]+b1v.w);
      hb[kq][nt] = pk8(lo, hi);
    }
  }
  const uint4* A2q = (const uint4*)(B2p + (size_t)a*(4*4*64*8));
  f32x4 accq[4][2] = {};
  #pragma unroll
  for (int kq = 0; kq < 4; ++kq){
    #pragma unroll
    for (int mC = 0; mC < 4; ++mC){
      U4 af; af.u = A2q[(kq*4 + mC)*64 + l];
      accq[mC][0] = mfma16(af.v, hb[kq][0], accq[mC][0]);
      accq[mC][1] = mfma16(af.v, hb[kq][1], accq[mC][1]);
    }
  }
  const float* bQ = f2b + a*C_ + lg*4;
  float4 qb[4];
  #pragma unroll
  for (int mC = 0; mC < 4; ++mC) qb[mC] = *(const float4*)(bQ + mC*16);
  #pragma unroll
  for (int nt = 0; nt < 2; ++nt){
    #pragma unroll
    for (int mC = 0; mC < 4; ++mC){
      qs[w][mC*16 + lg*4 + 0][l15] = accq[mC][nt][0] + qb[mC].x;
      qs[w][mC*16 + lg*4 + 1][l15] = accq[mC][nt][1] + qb[mC].y;
      qs[w][mC*16 + lg*4 + 2][l15] = accq[mC][nt][2] + qb[mC].z;
      qs[w][mC*16 + lg*4 + 3][l15] = accq[mC][nt][3] + qb[mC].w;
    }
    lgkm0();
    if (l < 16){
      const size_t row = (size_t)(btw + nt)*16 + l;
      const int id = ids[(size_t)a*B_ + row];
      out[(size_t)a*B_ + row] = qs[w][id][l];
    }
    lgkm0();
  }
}

extern "C" void kernel_launch(void* const* d_in, const int* in_sizes, int n_in,
                              void* d_out, int out_size, void* d_ws, size_t ws_size,
                              hipStream_t stream) {
  const float* obs  = (const float*)d_in[0];
  const float* act  = (const float*)d_in[1];
  const float* ggam = (const float*)d_in[2];
  const float* gbet = (const float*)d_in[3];
  const float* gW   = (const float*)d_in[4];
  const float* gb   = (const float*)d_in[5];
  const float* sgam = (const float*)d_in[6];
  const float* sbet = (const float*)d_in[7];
  const float* sW   = (const float*)d_in[8];
  const float* sb   = (const float*)d_in[9];
  const float* f1W  = (const float*)d_in[10];
  const float* f1b  = (const float*)d_in[11];
  const float* f2W  = (const float*)d_in[12];
  const float* f2b  = (const float*)d_in[13];
  // d_in[14]=Wq, d_in[15]=Wk dead (softmax over length-1 axis == 1)
  const float* Vm   = (const float*)d_in[16];
  float* out = (float*)d_out;

  char* base = (char*)d_ws; size_t off = 0;
  auto alloc = [&](size_t bytes) -> void* {
    off = (off + 255) & ~(size_t)255; void* p = base + off; off += bytes; return p;
  };
  float* psum    = (float*)alloc((size_t)A_*NCH*F_*4);
  float* psq     = (float*)alloc((size_t)A_*NCH*F_*4);
  float* zscale  = (float*)alloc((size_t)A_*F_*4);
  float* zshift  = (float*)alloc((size_t)A_*F_*4);
  float* gsb     = (float*)alloc((size_t)A_*256*4);
  __bf16* Ap     = (__bf16*)alloc((size_t)A_*10*16*64*8*2);
  __bf16* Vp     = (__bf16*)alloc((size_t)4*8*64*8*2);
  __bf16* B1p    = (__bf16*)alloc((size_t)A_*8*8*64*8*2);
  __bf16* B2p    = (__bf16*)alloc((size_t)A_*4*4*64*8*2);
  uint4* si_q    = (uint4*)alloc((size_t)A_*NBT*4*64*16);
  uint4* v_q     = (uint4*)alloc((size_t)A_*NBT*4*64*16);
  uint4* vsum_q  = (uint4*)alloc((size_t)NBT*4*64*16);
  int*   ids     = (int*)alloc((size_t)A_*B_*4);
  (void)ws_size; (void)in_sizes; (void)n_in; (void)out_size;

  k_stats_partial<<<dim3(NCH, A_), 320, 0, stream>>>(obs, act, psum, psq, ids);
  k_stats_final<<<A_, F_, 0, stream>>>(psum, psq, zscale, zshift);
  k_prep_pack<<<dim3(32, A_), 256, 0, stream>>>(gW, ggam, sW, sgam, f1W, f2W, Vm,
                                                zscale, Ap, Vp, B1p, B2p);
  k_prep_bias<<<dim3(2, A_), 256, 0, stream>>>(gW, gb, ggam, gbet, sW, sb, sgam, sbet,
                                               zshift, gsb);
  k_stageA<<<dim3(NBT/8, A_), 256, 0, stream>>>(obs, act, Ap, Vp, gsb, si_q, v_q);
  k_vsum<<<(NBT*4*64)/256, 256, 0, stream>>>(v_q, vsum_q);
  k_stageC<<<dim3(NBT/8, A_), 256, 0, stream>>>(v_q, si_q, vsum_q, B1p, B2p,
                                                 f1b, f2b, ids, out);
}